// Round 6
// baseline (665.402 us; speedup 1.0000x reference)
//
#include <hip/hip_runtime.h>
#include <math.h>

// CRF LLH, B=512,S=512,C=96.  QUAD grouping (halves R4's serial chain):
//   phase p (steps 4p+1..4p+4):  w <- (w . H'_p) * diag(e^{em[4p+4]})
//   H'_p = T d1 T d2 T d3 T = (P1 . diag(d2)) @ P2,  P1 = T d1 T,  P2 = T d3 T
// 512 blocks x 256 thr (1 consumer + 3 producer waves), 2 blocks/CU.
// Producers per phase: region1 = L1 (P1^T + P2 builds, 72 MFMA/wave),
// region2 = L2 (H build, 36 MFMA/wave, A/B frags read from LDS).
// P1 stored row-major by building P1^T = T^T d1 T^T; P2/H col-major.
// Scales 2^-7 (P1), 2^-7 (P2), 2^-1 (H fold) keep fp16 in range; the exact
// exponent rescale TRACKS them into sk, so the fast path must ADD the known
// debt back: +15/full phase, +8/triple tail (R5 bug: missing -> absmax was
// exactly 1913*ln2 bf16-rounded = 1328).  Cold (masked) path is unscaled ->
// no compensation.  Fragment maps / barrier protocol identical to R3/R4/R5.

#define BATCH 512
#define SEQ   512
#define NC    96
#define NTHR  256
#define CBYTES 208
#define PBYTES (NC * CBYTES)     // 19968 B per 96x96 fp16 matrix
#define LN2   0.69314718055994531f

typedef __fp16 half2v __attribute__((ext_vector_type(2)));
typedef __fp16 half8  __attribute__((ext_vector_type(8)));
typedef float  f32x4  __attribute__((ext_vector_type(4)));
typedef unsigned int uint2v __attribute__((ext_vector_type(2)));
typedef unsigned int uint4v __attribute__((ext_vector_type(4)));

#define BARRIER() asm volatile("s_waitcnt lgkmcnt(0)\n\ts_barrier" ::: "memory")

#define DPP_STEP_F(v, op, ctrl)                                              \
    v = op(v, __int_as_float(__builtin_amdgcn_update_dpp(                    \
            __float_as_int(v), __float_as_int(v), (ctrl), 0xf, 0xf, false)))

__device__ __forceinline__ float fadd_(float a, float b) { return a + b; }
__device__ __forceinline__ float wave_sum_all(float v) {
    DPP_STEP_F(v, fadd_, 0x111);
    DPP_STEP_F(v, fadd_, 0x112);
    DPP_STEP_F(v, fadd_, 0x114);
    DPP_STEP_F(v, fadd_, 0x118);
    DPP_STEP_F(v, fadd_, 0x142);
    DPP_STEP_F(v, fadd_, 0x143);
    return __int_as_float(__builtin_amdgcn_readlane(__float_as_int(v), 63));
}
__device__ __forceinline__ float wave_max_all(float v) {
    DPP_STEP_F(v, fmaxf, 0x111);
    DPP_STEP_F(v, fmaxf, 0x112);
    DPP_STEP_F(v, fmaxf, 0x114);
    DPP_STEP_F(v, fmaxf, 0x118);
    DPP_STEP_F(v, fmaxf, 0x142);
    DPP_STEP_F(v, fmaxf, 0x143);
    return __int_as_float(__builtin_amdgcn_readlane(__float_as_int(v), 63));
}

__device__ __forceinline__ unsigned pk2(float a, float b) {
    return __builtin_bit_cast(unsigned, __builtin_amdgcn_cvt_pkrtz(a, b));
}
__device__ __forceinline__ half2v bch(unsigned u) { return __builtin_bit_cast(half2v, u); }
__device__ __forceinline__ half8 h8(uint4v u) { return __builtin_bit_cast(half8, u); }
__device__ __forceinline__ float fdot2_(unsigned a, unsigned b, float c) {
    return __builtin_amdgcn_fdot2(bch(a), bch(b), c, false);
}
// one-column dot: sum_i sv[i] * col[i]
__device__ __forceinline__ float dotcol(const char* colbase, const uint4v* sv) {
    float a0 = 0.f, a1 = 0.f, a2 = 0.f, a3 = 0.f;
    #pragma unroll
    for (int q = 0; q < 12; ++q) {
        const uint4v x = *(const uint4v*)(colbase + 16 * q);
        a0 = fdot2_(sv[q].x, x.x, a0);
        a1 = fdot2_(sv[q].y, x.y, a1);
        a2 = fdot2_(sv[q].z, x.z, a2);
        a3 = fdot2_(sv[q].w, x.w, a3);
    }
    return (a0 + a1) + (a2 + a3);
}

__global__ __launch_bounds__(256)
void exp_pre_kernel(const float* __restrict__ em, __fp16* __restrict__ ex) {
    const size_t i = ((size_t)blockIdx.x * 256 + threadIdx.x) * 8;
    const float4 a = *(const float4*)(em + i);
    const float4 b = *(const float4*)(em + i + 4);
    uint4v r;
    r.x = pk2(__expf(a.x), __expf(a.y));
    r.y = pk2(__expf(a.z), __expf(a.w));
    r.z = pk2(__expf(b.x), __expf(b.y));
    r.w = pk2(__expf(b.z), __expf(b.w));
    *(uint4v*)(ex + i) = r;
}

template<int UEX>
__global__ __launch_bounds__(NTHR, 2)
void crf_quad_kernel(const float* __restrict__ em,      // (B,S,C)
                     const int*   __restrict__ tags,    // (B,S)
                     const int*   __restrict__ masks,   // (B,S)
                     const float* __restrict__ startT,  // (C)
                     const float* __restrict__ endT,    // (C)
                     const float* __restrict__ trans,   // (C,C)
                     const __fp16* __restrict__ exq,    // fp16 exp(em) or null
                     float*       __restrict__ out)     // scalar
{
    const int tid = threadIdx.x;
    const int l   = tid & 63;
    const int w   = tid >> 6;
    const int b   = blockIdx.x;

    __shared__ __align__(16) char  PB1[PBYTES];     // P1 row-major (= P1^T col-major)
    __shared__ __align__(16) char  PB2[PBYTES];     // P2 col-major
    __shared__ __align__(16) char  HB[2][PBYTES];   // H col-major, double buffer
    __shared__ __align__(16) __fp16 ST[96];         // state w

    const float*  em_b    = em    + (size_t)b * SEQ * NC;
    const int*    masks_b = masks + (size_t)b * SEQ;
    const __fp16* exq_b   = UEX ? (exq + (size_t)b * SEQ * NC) : (const __fp16*)0;

    if (w == 0) {
        // ===================== consumer =====================
        const bool act = (l < 48);

        float s0 = -1e30f, s1 = -1e30f;
        if (act) {
            s0 = startT[l]      + em_b[l];
            s1 = startT[l + 48] + em_b[l + 48];
        }
        const float M0 = wave_max_all(fmaxf(s0, s1));
        if (act) {
            ST[l]      = (__fp16)__expf(s0 - M0);
            ST[l + 48] = (__fp16)__expf(s1 - M0);
        }
        int sk = 0;

        auto ldE = [&](int row, float& x0, float& x1) {
            if (act) {
                if (UEX) {
                    x0 = (float)exq_b[(size_t)row * NC + l];
                    x1 = (float)exq_b[(size_t)row * NC + l + 48];
                } else {
                    x0 = __expf(em_b[(size_t)row * NC + l]);
                    x1 = __expf(em_b[(size_t)row * NC + l + 48]);
                }
            } else { x0 = 0.f; x1 = 0.f; }
        };

        // cold single step s vs global trans (exact; only when masks != all-1)
        auto sstep = [&](int s) {
            float v0 = 0.f, v1 = 0.f;
            if (act) {
                for (int i = 0; i < NC; ++i) {
                    const float wi = (float)ST[i];
                    v0 += wi * __expf(trans[i * NC + l]);
                    v1 += wi * __expf(trans[i * NC + l + 48]);
                }
                v0 *= __expf(em_b[(size_t)s * NC + l]);
                v1 *= __expf(em_b[(size_t)s * NC + l + 48]);
            }
            const float mx = wave_max_all(fmaxf(v0, v1));
            const unsigned ebx = (__float_as_uint(mx) >> 23) & 255u;
            sk += (int)ebx - 127;
            const float sc = __uint_as_float((254u - ebx) << 23);
            if (act) {
                ST[l]      = (__fp16)(v0 * sc);
                ST[l + 48] = (__fp16)(v1 * sc);
            }
        };

        // prefetch phase-0 trailing diag + masks
        float eC0, eC1;
        ldE(4, eC0, eC1);
        int m1 = masks_b[1], m2 = masks_b[2], m3 = masks_b[3], m4 = masks_b[4];

        BARRIER();   // prologue barrier (producers: after L1(0))

        #pragma unroll 1
        for (int p = 0; p <= 127; ++p) {
            BARRIER();   // phase top: H[p] ready
            // ---- region 1: full matvec vs H[p&1]
            uint4v sv[12];
            const uint4v* stp = (const uint4v*)ST;
            #pragma unroll
            for (int q = 0; q < 12; ++q) sv[q] = stp[q];
            float u0 = 0.f, u1 = 0.f;
            __builtin_amdgcn_s_setprio(1);
            if (act) {
                const char* hb = HB[p & 1];
                u0 = dotcol(hb + l * CBYTES, sv);
                u1 = dotcol(hb + (l + 48) * CBYTES, sv);
            }
            __builtin_amdgcn_s_setprio(0);
            BARRIER();   // mid
            // ---- region 2: finish + rescale + prefetch next
            const bool last = (p == 127);
            const bool fast = last ? (m1 && m2 && m3) : (m1 && m2 && m3 && m4);
            if (fast) {
                u0 *= eC0; u1 *= eC1;
                const float mx = wave_max_all(fmaxf(u0, u1));
                const unsigned ebx = (__float_as_uint(mx) >> 23) & 255u;
                // +15/+8: compensate the known producer scales 2^-15 (full
                // quad) / 2^-8 (triple tail) baked into H_stored (R5 fix).
                sk += (int)ebx - 127 + (last ? 8 : 15);
                const float sc = __uint_as_float((254u - ebx) << 23);
                if (act) {
                    ST[l]      = (__fp16)(u0 * sc);
                    ST[l + 48] = (__fp16)(u1 * sc);
                }
            } else {
                const int ns = last ? 3 : 4;
                for (int j = 0; j < ns; ++j) {
                    const int s = 4 * p + 1 + j;
                    const int mkj = (j == 0) ? m1 : (j == 1) ? m2 : (j == 2) ? m3 : m4;
                    if (mkj) sstep(s);
                }
            }
            if (p < 127) {
                const int pn = p + 1;
                ldE((pn == 127) ? 511 : (4 * pn + 4), eC0, eC1);
                m1 = masks_b[4 * pn + 1];
                m2 = masks_b[4 * pn + 2];
                m3 = masks_b[4 * pn + 3];
                m4 = (pn == 127) ? 1 : masks_b[4 * pn + 4];
            }
        }

        // ---- denominator
        {
            float d0 = 0.f, d1 = 0.f;
            if (act) {
                d0 = (float)ST[l]      * __expf(endT[l]);
                d1 = (float)ST[l + 48] * __expf(endT[l + 48]);
            }
            const float dv = wave_sum_all(d0 + d1);
            if (l == 0)
                atomicAdd(out, -(M0 + (float)sk * LN2 + __logf(dv)) * (1.0f / (float)BATCH));
        }
    } else {
        // ===================== producers =====================
        const int lidx = l & 15;
        const int g    = l >> 4;
        const int nt0  = 2 * (w - 1);    // this wave's two 16-col output tiles

        // RowF[r][c][e] = exp(T[16r+lidx][32c+8g+e])   (row-type frags)
        // ColF[r][c][e] = exp(T[32c+8g+e][16r+lidx])   (col-type frags)
        half8 RowF[6][3], ColF[6][3];
        #pragma unroll
        for (int r = 0; r < 6; ++r)
            #pragma unroll
            for (int c = 0; c < 3; ++c) {
                half8 va, vb;
                #pragma unroll
                for (int e = 0; e < 8; ++e) {
                    va[e] = (__fp16)__expf(trans[(16 * r + lidx) * NC + 32 * c + 8 * g + e]);
                    vb[e] = (__fp16)__expf(trans[(32 * c + 8 * g + e) * NC + 16 * r + lidx]);
                }
                RowF[r][c] = va;
                ColF[r][c] = vb;
            }

        const half8 SC7 = { (__fp16)0.0078125f, (__fp16)0.0078125f, (__fp16)0.0078125f, (__fp16)0.0078125f,
                            (__fp16)0.0078125f, (__fp16)0.0078125f, (__fp16)0.0078125f, (__fp16)0.0078125f };
        const half8 SC1 = { (__fp16)0.5f, (__fp16)0.5f, (__fp16)0.5f, (__fp16)0.5f,
                            (__fp16)0.5f, (__fp16)0.5f, (__fp16)0.5f, (__fp16)0.5f };

        auto ldd = [&](int row, uint4v d[3]) {
            if (UEX) {
                const char* p = (const char*)exq_b + (size_t)row * 192 + 16 * g;
                d[0] = *(const uint4v*)(p);
                d[1] = *(const uint4v*)(p + 64);
                d[2] = *(const uint4v*)(p + 128);
            } else {
                const float* p = em_b + (size_t)row * NC + 8 * g;
                #pragma unroll
                for (int c = 0; c < 3; ++c) {
                    const float4 a = *(const float4*)(p + 32 * c);
                    const float4 bq = *(const float4*)(p + 32 * c + 4);
                    uint4v r_;
                    r_.x = pk2(__expf(a.x), __expf(a.y));
                    r_.y = pk2(__expf(a.z), __expf(a.w));
                    r_.z = pk2(__expf(bq.x), __expf(bq.y));
                    r_.w = pk2(__expf(bq.z), __expf(bq.w));
                    d[c] = r_;
                }
            }
        };

        // L1: P1^T -> PB1 (always); P2 -> PB2 (unless triple tail)
        auto buildP = [&](const uint4v dA[3], const uint4v dB[3], bool tail) {
            half8 dAs[3], dBs[3];
            #pragma unroll
            for (int c = 0; c < 3; ++c) { dAs[c] = h8(dA[c]) * SC7; dBs[c] = h8(dB[c]) * SC7; }
            const f32x4 z = {0.f, 0.f, 0.f, 0.f};
            #pragma unroll
            for (int ntL = 0; ntL < 2; ++ntL) {
                const int nt = nt0 + ntL;
                // P1^T: A = ColF[r], B = dA (.) RowF[nt]
                half8 b0 = dAs[0] * RowF[nt][0];
                half8 b1 = dAs[1] * RowF[nt][1];
                half8 b2 = dAs[2] * RowF[nt][2];
                char* cp = PB1 + (16 * nt + lidx) * CBYTES + 8 * g;
                #pragma unroll
                for (int r = 0; r < 6; ++r) {
                    f32x4 acc = __builtin_amdgcn_mfma_f32_16x16x32_f16(ColF[r][0], b0, z, 0, 0, 0);
                    acc = __builtin_amdgcn_mfma_f32_16x16x32_f16(ColF[r][1], b1, acc, 0, 0, 0);
                    acc = __builtin_amdgcn_mfma_f32_16x16x32_f16(ColF[r][2], b2, acc, 0, 0, 0);
                    uint2v wv; wv.x = pk2(acc[0], acc[1]); wv.y = pk2(acc[2], acc[3]);
                    *(uint2v*)(cp + 32 * r) = wv;
                }
            }
            if (!tail) {
                #pragma unroll
                for (int ntL = 0; ntL < 2; ++ntL) {
                    const int nt = nt0 + ntL;
                    // P2: A = RowF[r], B = dB (.) ColF[nt]
                    half8 b0 = dBs[0] * ColF[nt][0];
                    half8 b1 = dBs[1] * ColF[nt][1];
                    half8 b2 = dBs[2] * ColF[nt][2];
                    char* cp = PB2 + (16 * nt + lidx) * CBYTES + 8 * g;
                    #pragma unroll
                    for (int r = 0; r < 6; ++r) {
                        f32x4 acc = __builtin_amdgcn_mfma_f32_16x16x32_f16(RowF[r][0], b0, z, 0, 0, 0);
                        acc = __builtin_amdgcn_mfma_f32_16x16x32_f16(RowF[r][1], b1, acc, 0, 0, 0);
                        acc = __builtin_amdgcn_mfma_f32_16x16x32_f16(RowF[r][2], b2, acc, 0, 0, 0);
                        uint2v wv; wv.x = pk2(acc[0], acc[1]); wv.y = pk2(acc[2], acc[3]);
                        *(uint2v*)(cp + 32 * r) = wv;
                    }
                }
            }
        };

        // L2: H = (P1 . diag(dC)) @ (tail ? T : P2)  -> HB[hsel]
        auto buildH = [&](const uint4v dC[3], int hsel, bool tail) {
            half8 dCs[3];
            #pragma unroll
            for (int c = 0; c < 3; ++c) dCs[c] = h8(dC[c]) * SC1;
            half8 Bf[2][3];
            #pragma unroll
            for (int ntL = 0; ntL < 2; ++ntL) {
                const int nt = nt0 + ntL;
                #pragma unroll
                for (int c = 0; c < 3; ++c) {
                    if (tail) Bf[ntL][c] = ColF[nt][c];
                    else      Bf[ntL][c] = h8(*(const uint4v*)(PB2 + (16 * nt + lidx) * CBYTES + 64 * c + 16 * g));
                }
            }
            const f32x4 z = {0.f, 0.f, 0.f, 0.f};
            char* hb = HB[hsel];
            #pragma unroll
            for (int r = 0; r < 6; ++r) {
                const char* ap = PB1 + (16 * r + lidx) * CBYTES + 16 * g;
                const half8 A0 = h8(*(const uint4v*)(ap))       * dCs[0];
                const half8 A1 = h8(*(const uint4v*)(ap + 64))  * dCs[1];
                const half8 A2 = h8(*(const uint4v*)(ap + 128)) * dCs[2];
                #pragma unroll
                for (int ntL = 0; ntL < 2; ++ntL) {
                    f32x4 acc = __builtin_amdgcn_mfma_f32_16x16x32_f16(A0, Bf[ntL][0], z, 0, 0, 0);
                    acc = __builtin_amdgcn_mfma_f32_16x16x32_f16(A1, Bf[ntL][1], acc, 0, 0, 0);
                    acc = __builtin_amdgcn_mfma_f32_16x16x32_f16(A2, Bf[ntL][2], acc, 0, 0, 0);
                    uint2v wv; wv.x = pk2(acc[0], acc[1]); wv.y = pk2(acc[2], acc[3]);
                    *(uint2v*)(hb + (16 * (nt0 + ntL) + lidx) * CBYTES + 32 * r + 8 * g) = wv;
                }
            }
        };

        // prologue: build phase 0 (P from rows 1,3; H from row 2)
        uint4v dA[3], dB[3], dC[3], nA[3], nB[3], nC[3];
        ldd(1, dA); ldd(3, dB); ldd(2, dC);
        buildP(dA, dB, false);
        ldd(5, nA); ldd(7, nB); ldd(6, nC);   // q=1 prefetch
        BARRIER();
        buildH(dC, 0, false);

        #pragma unroll 1
        for (int p = 0; p <= 127; ++p) {
            BARRIER();   // phase top
            const int q = p + 1;
            #pragma unroll
            for (int c = 0; c < 3; ++c) { dA[c] = nA[c]; dB[c] = nB[c]; dC[c] = nC[c]; }
            if (q <= 127) buildP(dA, dB, q == 127);
            if (q <= 126) {
                const int qq = q + 1;
                const int rb = (4 * qq + 3 > 511) ? 511 : (4 * qq + 3);
                ldd(4 * qq + 1, nA); ldd(rb, nB); ldd(4 * qq + 2, nC);
            }
            BARRIER();   // mid
            if (q <= 127) buildH(dC, q & 1, q == 127);
        }

        // ---- numerator on wave 1 (tag-path gather for this chain)
        if (w == 1) {
            const int* tb = tags + (size_t)b * SEQ;
            float nsum = 0.f, msum = 0.f;
            #pragma unroll
            for (int kk = 0; kk < 8; ++kk) {
                const int s  = l + 64 * kk;
                const int tg = tb[s];
                const int mk = masks_b[s];
                msum += mk ? 1.f : 0.f;
                if (s == 0) {
                    nsum += startT[tg] + em_b[tg];
                } else if (mk) {
                    nsum += trans[tb[s - 1] * NC + tg] + em_b[(size_t)s * NC + tg];
                }
            }
            nsum = wave_sum_all(nsum);
            msum = wave_sum_all(msum);
            if (l == 0) {
                const int cnt  = (int)msum;
                const int last = tb[cnt - 1];
                atomicAdd(out, (nsum + endT[last]) * (1.0f / (float)BATCH));
            }
        }
    }
}

extern "C" void kernel_launch(void* const* d_in, const int* in_sizes, int n_in,
                              void* d_out, int out_size, void* d_ws, size_t ws_size,
                              hipStream_t stream) {
    const float* em     = (const float*)d_in[0];
    const int*   tags   = (const int*)  d_in[1];
    const int*   masks  = (const int*)  d_in[2];
    const float* startT = (const float*)d_in[3];
    const float* endT   = (const float*)d_in[4];
    const float* trans  = (const float*)d_in[5];
    float* out = (float*)d_out;

    (void)hipMemsetAsync(out, 0, sizeof(float), stream);

    const size_t exbytes = (size_t)BATCH * SEQ * NC * sizeof(__fp16);
    if (d_ws != nullptr && ws_size >= exbytes) {
        const int nelem8 = BATCH * SEQ * NC / 8;          // 3145728
        exp_pre_kernel<<<nelem8 / 256, 256, 0, stream>>>(em, (__fp16*)d_ws);
        crf_quad_kernel<1><<<BATCH, NTHR, 0, stream>>>(
            em, tags, masks, startT, endT, trans, (const __fp16*)d_ws, out);
    } else {
        crf_quad_kernel<0><<<BATCH, NTHR, 0, stream>>>(
            em, tags, masks, startT, endT, trans, (const __fp16*)0, out);
    }
}